// Round 1
// baseline (357.433 us; speedup 1.0000x reference)
//
#include <hip/hip_runtime.h>
#include <math.h>

#ifndef M_PI
#define M_PI 3.14159265358979323846
#endif

// Static problem config (mirrors reference)
#define SS   129                 // density cube side
#define LL   224                 // padded/rotation cube side = ceil(129*sqrt(3))
#define LL2  (LL*LL)
#define LL3  (LL*LL*LL)
#define SS2  (SS*SS)
#define SS3  (SS*SS*SS)
#define CABS 0.2f
#define PAD  48                  // LL/2 - SS/2 = 112 - 64

struct Mat3 { float m[9]; };

// linspace(-1, 1, 224)[i]
__device__ __forceinline__ float nrm(int i) {
    return fmaf((float)i, 2.0f / 223.0f, -1.0f);
}

// padded-volume fetch: zero outside the centered SS^3 region
__device__ __forceinline__ float fetch_d(const float* __restrict__ d, int z, int y, int x) {
    unsigned zz = (unsigned)(z - PAD), yy = (unsigned)(y - PAD), xx = (unsigned)(x - PAD);
    return (zz < (unsigned)SS && yy < (unsigned)SS && xx < (unsigned)SS)
        ? d[((int)zz * SS + (int)yy) * SS + (int)xx] : 0.0f;
}

// transmittance-volume fetch: zero outside [0,LL)^3 (reference zero-pads here too)
__device__ __forceinline__ float fetch_T(const float* __restrict__ T, int z, int y, int x) {
    unsigned zz = (unsigned)z, yy = (unsigned)y, xx = (unsigned)x;
    return (zz < (unsigned)LL && yy < (unsigned)LL && xx < (unsigned)LL)
        ? T[((int)zz * LL + (int)yy) * LL + (int)xx] : 0.0f;
}

__device__ __forceinline__ float tri_d(const float* __restrict__ d, float qz, float qy, float qx) {
    int x0 = (int)floorf(qx), y0 = (int)floorf(qy), z0 = (int)floorf(qz);
    float wx = qx - (float)x0, wy = qy - (float)y0, wz = qz - (float)z0;
    float c000 = fetch_d(d, z0,     y0,     x0    );
    float c001 = fetch_d(d, z0,     y0,     x0 + 1);
    float c010 = fetch_d(d, z0,     y0 + 1, x0    );
    float c011 = fetch_d(d, z0,     y0 + 1, x0 + 1);
    float c100 = fetch_d(d, z0 + 1, y0,     x0    );
    float c101 = fetch_d(d, z0 + 1, y0,     x0 + 1);
    float c110 = fetch_d(d, z0 + 1, y0 + 1, x0    );
    float c111 = fetch_d(d, z0 + 1, y0 + 1, x0 + 1);
    float a00 = c000 + wx * (c001 - c000);
    float a01 = c010 + wx * (c011 - c010);
    float a10 = c100 + wx * (c101 - c100);
    float a11 = c110 + wx * (c111 - c110);
    float b0  = a00 + wy * (a01 - a00);
    float b1  = a10 + wy * (a11 - a10);
    return b0 + wz * (b1 - b0);
}

__device__ __forceinline__ float tri_T(const float* __restrict__ T, float qz, float qy, float qx) {
    int x0 = (int)floorf(qx), y0 = (int)floorf(qy), z0 = (int)floorf(qz);
    float wx = qx - (float)x0, wy = qy - (float)y0, wz = qz - (float)z0;
    float c000 = fetch_T(T, z0,     y0,     x0    );
    float c001 = fetch_T(T, z0,     y0,     x0 + 1);
    float c010 = fetch_T(T, z0,     y0 + 1, x0    );
    float c011 = fetch_T(T, z0,     y0 + 1, x0 + 1);
    float c100 = fetch_T(T, z0 + 1, y0,     x0    );
    float c101 = fetch_T(T, z0 + 1, y0,     x0 + 1);
    float c110 = fetch_T(T, z0 + 1, y0 + 1, x0    );
    float c111 = fetch_T(T, z0 + 1, y0 + 1, x0 + 1);
    float a00 = c000 + wx * (c001 - c000);
    float a01 = c010 + wx * (c011 - c010);
    float a10 = c100 + wx * (c101 - c100);
    float a11 = c110 + wx * (c111 - c110);
    float b0  = a00 + wy * (a01 - a00);
    float b1  = a10 + wy * (a11 - a10);
    return b0 + wz * (b1 - b0);
}

// K1: rotated density: T[z][y][x] = trilinear(pad(d), R @ base(x,y,z))
__global__ __launch_bounds__(256) void k_rot_density(const float* __restrict__ d,
                                                     float* __restrict__ T, Mat3 R) {
    int i = blockIdx.x * 256 + threadIdx.x;
    if (i >= LL3) return;
    int x = i % LL; int r = i / LL; int y = r % LL; int z = r / LL;
    float bx = nrm(x), by = nrm(y), bz = nrm(z);
    float sx = fmaf(R.m[0], bx, fmaf(R.m[1], by, R.m[2] * bz));
    float sy = fmaf(R.m[3], bx, fmaf(R.m[4], by, R.m[5] * bz));
    float sz = fmaf(R.m[6], bx, fmaf(R.m[7], by, R.m[8] * bz));
    float qx = fmaf(sx, 111.5f, 111.5f);   // (s+1)*0.5*(LL-1)
    float qy = fmaf(sy, 111.5f, 111.5f);
    float qz = fmaf(sz, 111.5f, 111.5f);
    T[i] = tri_d(d, qz, qy, qx);
}

// K2: in-place reverse cumulative sum along z + exp(-c*.)
__global__ __launch_bounds__(256) void k_scan_exp(float* __restrict__ T) {
    int col = blockIdx.x * 256 + threadIdx.x;
    if (col >= LL2) return;
    float run = 0.0f;
    #pragma unroll 8
    for (int z = LL - 1; z >= 0; --z) {
        int idx = z * LL2 + col;
        run += T[idx];
        T[idx] = __expf(-CABS * run);
    }
}

// K3: rotate transmittance back (with RT = R^T), cropped to the SS^3 center
__global__ __launch_bounds__(256) void k_rot_back(const float* __restrict__ T,
                                                  float* __restrict__ U, Mat3 RT) {
    int i = blockIdx.x * 256 + threadIdx.x;
    if (i >= SS3) return;
    int x = i % SS; int r = i / SS; int y = r % SS; int z = r / SS;
    float bx = nrm(x + PAD), by = nrm(y + PAD), bz = nrm(z + PAD);
    float sx = fmaf(RT.m[0], bx, fmaf(RT.m[1], by, RT.m[2] * bz));
    float sy = fmaf(RT.m[3], bx, fmaf(RT.m[4], by, RT.m[5] * bz));
    float sz = fmaf(RT.m[6], bx, fmaf(RT.m[7], by, RT.m[8] * bz));
    float qx = fmaf(sx, 111.5f, 111.5f);
    float qy = fmaf(sy, 111.5f, 111.5f);
    float qz = fmaf(sz, 111.5f, 111.5f);
    U[i] = tri_T(T, qz, qy, qx);
}

// K4: composite along view ray: out[ch][h][w] = clip(c * sum_z d*t*(u0*rgb0+u1*rgb1))
__global__ __launch_bounds__(256) void k_finalize(const float* __restrict__ d,
                                                  const float* __restrict__ U0,
                                                  const float* __restrict__ U1,
                                                  float* __restrict__ out,
                                                  float r0r, float r0g, float r0b,
                                                  float r1r, float r1g, float r1b) {
    int col = blockIdx.x * 256 + threadIdx.x;
    if (col >= SS2) return;
    float run = 0.0f, a0 = 0.0f, a1 = 0.0f;
    #pragma unroll 4
    for (int z = SS - 1; z >= 0; --z) {
        int idx = z * SS2 + col;
        float dv = d[idx];
        run += dv;
        float w = dv * __expf(-CABS * run);
        a0 = fmaf(w, U0[idx], a0);
        a1 = fmaf(w, U1[idx], a1);
    }
    float o0 = CABS * (a0 * r0r + a1 * r1r);
    float o1 = CABS * (a0 * r0g + a1 * r1g);
    float o2 = CABS * (a0 * r0b + a1 * r1b);
    out[0 * SS2 + col] = fminf(fmaxf(o0, 0.0f), 1.0f);
    out[1 * SS2 + col] = fminf(fmaxf(o1, 0.0f), 1.0f);
    out[2 * SS2 + col] = fminf(fmaxf(o2, 0.0f), 1.0f);
}

// ---- fallback path (small workspace): fuse back-rotation into the compositor ----
__global__ __launch_bounds__(256) void k_fused_back(const float* __restrict__ T,
                                                    const float* __restrict__ d,
                                                    float* __restrict__ LA, Mat3 RT,
                                                    float cr, float cg, float cb, int first) {
    int col = blockIdx.x * 256 + threadIdx.x;
    if (col >= SS2) return;
    int y = col / SS, x = col % SS;
    float bx = nrm(x + PAD), by = nrm(y + PAD);
    // q_k(z) = C_k + (z+PAD) * RT[k][2]   (normalized spacing == 1 voxel)
    float Cx = 111.5f * (RT.m[0] * bx + RT.m[1] * by - RT.m[2] + 1.0f);
    float Cy = 111.5f * (RT.m[3] * bx + RT.m[4] * by - RT.m[5] + 1.0f);
    float Cz = 111.5f * (RT.m[6] * bx + RT.m[7] * by - RT.m[8] + 1.0f);
    float run = 0.0f, acc = 0.0f;
    for (int z = SS - 1; z >= 0; --z) {
        float fz = (float)(z + PAD);
        float qx = fmaf(fz, RT.m[2], Cx);
        float qy = fmaf(fz, RT.m[5], Cy);
        float qz = fmaf(fz, RT.m[8], Cz);
        float u = tri_T(T, qz, qy, qx);
        float dv = d[z * SS2 + col];
        run += dv;
        acc = fmaf(dv * __expf(-CABS * run), u, acc);
    }
    if (first) {
        LA[0 * SS2 + col] = acc * cr;
        LA[1 * SS2 + col] = acc * cg;
        LA[2 * SS2 + col] = acc * cb;
    } else {
        LA[0 * SS2 + col] += acc * cr;
        LA[1 * SS2 + col] += acc * cg;
        LA[2 * SS2 + col] += acc * cb;
    }
}

__global__ __launch_bounds__(256) void k_clip(const float* __restrict__ LA, float* __restrict__ out) {
    int i = blockIdx.x * 256 + threadIdx.x;
    if (i < 3 * SS2) out[i] = fminf(fmaxf(CABS * LA[i], 0.0f), 1.0f);
}

// host: build R (ypr) and its transpose (== rot_matrix(-y,-p,'rpy')) exactly as reference
static void light_mats(const double ld_in[3], Mat3& R, Mat3& RT) {
    double n = sqrt(ld_in[0]*ld_in[0] + ld_in[1]*ld_in[1] + ld_in[2]*ld_in[2]);
    double l0 = ld_in[0]/n, l1 = ld_in[1]/n, l2 = ld_in[2]/n;
    double yv = -asin(l0);
    if (l2 < 0) yv = -M_PI - yv;
    double yd = yv * 180.0 / M_PI, pd = asin(l1) * 180.0 / M_PI;  // deg round-trip as in ref
    double yr = yd * M_PI / 180.0, pr = pd * M_PI / 180.0;
    float cy = (float)cos(yr), sy = (float)sin(yr), cp = (float)cos(pr), sp = (float)sin(pr);
    // R = Ry @ Rp, f32 entry products (matches numpy f32 matmul of these sparse factors)
    float m[9] = { cy,  sy*sp,  sy*cp,
                   0.f, cp,    -sp,
                  -sy,  cy*sp,  cy*cp };
    for (int i = 0; i < 9; ++i) R.m[i] = m[i];
    // second rotation matrix Rp(-p)@Ry(-y) == R^T (same f32 products)
    RT.m[0] = m[0]; RT.m[1] = m[3]; RT.m[2] = m[6];
    RT.m[3] = m[1]; RT.m[4] = m[4]; RT.m[5] = m[7];
    RT.m[6] = m[2]; RT.m[7] = m[5]; RT.m[8] = m[8];
}

extern "C" void kernel_launch(void* const* d_in, const int* in_sizes, int n_in,
                              void* d_out, int out_size, void* d_ws, size_t ws_size,
                              hipStream_t stream) {
    const float* d = (const float*)d_in[0];
    float* out = (float*)d_out;
    float* T = (float*)d_ws;

    const double dirs[2][3] = { {2.0, 1.0, 1.0}, {-1.0, 0.5, 0.0} };
    const float rgb[2][3] = { {1.0f, 69.0f/255.0f, 25.0f/255.0f},
                              {227.0f/255.0f, 1.0f, 66.0f/255.0f} };

    const size_t need_fast = (size_t)(LL3 + 2 * SS3) * sizeof(float);
    bool fast = ws_size >= need_fast;

    if (fast) {
        float* U0 = T + LL3;
        float* U1 = U0 + SS3;
        for (int l = 0; l < 2; ++l) {
            Mat3 R, RT;
            light_mats(dirs[l], R, RT);
            k_rot_density<<<(LL3 + 255) / 256, 256, 0, stream>>>(d, T, R);
            k_scan_exp  <<<(LL2 + 255) / 256, 256, 0, stream>>>(T);
            k_rot_back  <<<(SS3 + 255) / 256, 256, 0, stream>>>(T, l ? U1 : U0, RT);
        }
        k_finalize<<<(SS2 + 255) / 256, 256, 0, stream>>>(d, U0, U1, out,
            rgb[0][0], rgb[0][1], rgb[0][2], rgb[1][0], rgb[1][1], rgb[1][2]);
    } else {
        float* LA = T + LL3;   // 3*SS2 floats
        for (int l = 0; l < 2; ++l) {
            Mat3 R, RT;
            light_mats(dirs[l], R, RT);
            k_rot_density<<<(LL3 + 255) / 256, 256, 0, stream>>>(d, T, R);
            k_scan_exp  <<<(LL2 + 255) / 256, 256, 0, stream>>>(T);
            k_fused_back<<<(SS2 + 255) / 256, 256, 0, stream>>>(T, d, LA, RT,
                rgb[l][0], rgb[l][1], rgb[l][2], l == 0);
        }
        k_clip<<<(3 * SS2 + 255) / 256, 256, 0, stream>>>(LA, out);
    }
}